// Round 13
// baseline (230.504 us; speedup 1.0000x reference)
//
#include <hip/hip_runtime.h>

typedef float floatx4 __attribute__((ext_vector_type(4)));
typedef __bf16 bfx8 __attribute__((ext_vector_type(8)));
typedef __bf16 bfx4 __attribute__((ext_vector_type(4)));

// Problem constants
constexpr int B_ = 2, S_ = 2048, H_ = 2048, NH_ = 16, NKV_ = 4, HD_ = 64;
constexpr int M_ = B_ * S_;               // 4096 rows
constexpr int NQKV_ = NH_ * HD_ + 2 * NKV_ * HD_; // 1536
constexpr int HQ_ = NH_ * HD_;            // 1024
// Pitches: 128B-aligned (no cache-line straddle on 128B DMA row-chunks) AND an
// odd multiple of 64 elements (33x128B / 17x128B) to keep channel spread.
constexpr int XP_ = 2112;  // xbf / wqkvT pitch (4224B = 33*128)
constexpr int AP_ = 1088;  // attn-out / woT pitch (2176B = 17*128)
constexpr int VP_ = 2112;  // V-transposed pitch

#define GLB(p) ((const __attribute__((address_space(1))) void*)(p))
#define LDS(p) ((__attribute__((address_space(3))) void*)(p))

// ---------------- fused prep: fp32->bf16 cast of x + wq/wk/wv transposes ----------------
// (wo transpose moved into the attn launch: it is needed only by gemm2, which runs
//  after attn — hosting it there takes it off the prep->gemm1 critical path and lets
//  it fill attn's tail occupancy holes.)
__global__ __launch_bounds__(256) void prep_kernel(const float* __restrict__ x,
                                                   const float* __restrict__ wq,
                                                   const float* __restrict__ wk,
                                                   const float* __restrict__ wv,
                                                   __bf16* __restrict__ xbf,
                                                   __bf16* __restrict__ wqkvT) {
  __shared__ float tile[32][33];
  int bid = blockIdx.x;
  if (bid < M_) {
    // ---- cast branch ----
    const float4* s = (const float4*)(x + (size_t)bid * H_);
    __bf16* d = xbf + (size_t)bid * XP_;
#pragma unroll
    for (int i = 0; i < 2; i++) {
      int c = i * 256 + threadIdx.x;
      float4 v = s[c];
      bfx4 o;
      o[0] = (__bf16)v.x; o[1] = (__bf16)v.y; o[2] = (__bf16)v.z; o[3] = (__bf16)v.w;
      *(bfx4*)(d + c * 4) = o;
    }
    return;
  }
  bid -= M_;
  const float* src; int N, dstOff, nbx;
  if (bid < 2048)      { src = wq; N = 1024; dstOff = 0;    nbx = 32; }
  else if (bid < 2560) { bid -= 2048; src = wk; N = 256; dstOff = 1024; nbx = 8; }
  else                 { bid -= 2560; src = wv; N = 256; dstOff = 1280; nbx = 8; }
  int n0 = (bid % nbx) * 32, k0 = (bid / nbx) * 32;
  int tx = threadIdx.x & 31, ty = threadIdx.x >> 5; // (32,8) layout
#pragma unroll
  for (int r = 0; r < 32; r += 8)
    tile[ty + r][tx] = src[(size_t)(k0 + ty + r) * N + n0 + tx];
  __syncthreads();
#pragma unroll
  for (int r = 0; r < 32; r += 8)
    wqkvT[(size_t)(n0 + ty + r + dstOff) * XP_ + k0 + tx] = (__bf16)tile[tx][ty + r];
}

// ---------------- fused QKV GEMM + RMSNorm + RoPE + attention-layout epilogue -----------
// R10-exact (best measured, 46.2us): 128x128 tile, BK=64, 4 waves (2x2), 2-phase LDS
// double-buffer with __syncthreads, 384 blocks + chunked XCD swizzle (FETCH 75.9->33.9MB).
// R11 proved counted-vmcnt adds nothing here: the stall is DMA-issue/L2-service
// throughput, not the barrier drain.
__global__ __launch_bounds__(256) void gemm_qkv_fused(const __bf16* __restrict__ A,
                                                      const __bf16* __restrict__ Bt,
                                                      const float* __restrict__ cosT,
                                                      const float* __restrict__ sinT,
                                                      const float* __restrict__ qw,
                                                      const float* __restrict__ kw,
                                                      __bf16* __restrict__ Qo,
                                                      __bf16* __restrict__ Ko,
                                                      __bf16* __restrict__ VTo) {
  __shared__ __align__(16) __bf16 As[2][128 * 64];
  __shared__ __align__(16) __bf16 Bs[2][128 * 64];
  int wid = threadIdx.x >> 6, lane = threadIdx.x & 63;
  int l15 = lane & 15, quad = lane >> 4;
  int wm = (wid >> 1) * 64, wn = (wid & 1) * 64;
  // chunked XCD swizzle (384 = 8 x 48, bijective)
  int lin = blockIdx.x + 12 * blockIdx.y;
  int virt = (lin & 7) * 48 + (lin >> 3);
  int m0 = (virt / 12) * 128, n0 = (virt % 12) * 128;
  int srow_off = lane >> 3;
  int gphys = lane & 7;
  floatx4 acc[4][4] = {};

  // ---- staging helper (issue only; no wait) ----
  auto stage = [&](int bufi, int kb) {
#pragma unroll
    for (int j = 0; j < 4; j++) {
      int rbase = wid * 32 + j * 8;
      int row = rbase + srow_off;
      int glog = gphys ^ (row & 7);
      const __bf16* ga = &A[(size_t)(m0 + row) * XP_ + kb + glog * 8];
      const __bf16* gb = &Bt[(size_t)(n0 + row) * XP_ + kb + glog * 8];
      __builtin_amdgcn_global_load_lds(GLB(ga), LDS(&As[bufi][rbase * 64]), 16, 0, 0);
      __builtin_amdgcn_global_load_lds(GLB(gb), LDS(&Bs[bufi][rbase * 64]), 16, 0, 0);
    }
  };

  stage(0, 0);
  __syncthreads(); // buf0 ready
  int buf = 0;
  for (int kb = 0; kb < H_; kb += 64) {
    if (kb + 64 < H_) stage(buf ^ 1, kb + 64); // prefetch next tile (overlaps compute)
#pragma unroll
    for (int kk = 0; kk < 64; kk += 32) {
      int cgq = (kk >> 3) + quad;
      bfx8 af[4], bfr[4];
#pragma unroll
      for (int mi = 0; mi < 4; mi++) {
        int row = wm + mi * 16 + l15;
        af[mi] = *(const bfx8*)&As[buf][row * 64 + (cgq ^ (row & 7)) * 8];
      }
#pragma unroll
      for (int ni = 0; ni < 4; ni++) {
        int row = wn + ni * 16 + l15;
        bfr[ni] = *(const bfx8*)&Bs[buf][row * 64 + (cgq ^ (row & 7)) * 8];
      }
#pragma unroll
      for (int mi = 0; mi < 4; mi++)
#pragma unroll
        for (int ni = 0; ni < 4; ni++)
          acc[mi][ni] = __builtin_amdgcn_mfma_f32_16x16x32_bf16(af[mi], bfr[ni], acc[mi][ni], 0, 0, 0);
    }
    __syncthreads(); // drains remaining prefetch + protects buf overwrite next iter
    buf ^= 1;
  }
  // ---------------- fused epilogue ----------------
  // acc[mi][ni][r] = C[m0+wm+mi*16+quad*4+r][n0+wn+ni*16+l15]
  int hh = (n0 + wn) >> 6;   // wave-uniform head id: 0..15 q, 16..19 k, 20..23 v
  int b = m0 >> 11;          // whole block within one batch (m0 mult of 128)
  if (hh < 20) {
    const float* wptr = (hh < 16) ? qw : kw;
    float wv4[4];
#pragma unroll
    for (int ni = 0; ni < 4; ni++) wv4[ni] = wptr[ni * 16 + l15];
    __bf16* outp = (hh < 16) ? (Qo + (((size_t)b * NH_ + hh) * S_) * HD_)
                             : (Ko + (((size_t)b * NKV_ + (hh - 16)) * S_) * HD_);
#pragma unroll
    for (int mi = 0; mi < 4; mi++) {
#pragma unroll
      for (int r = 0; r < 4; r++) {
        // RMSNorm: sum of squares over the head's 64 cols (4 regs x 16 lanes)
        float ssum = acc[mi][0][r] * acc[mi][0][r] + acc[mi][1][r] * acc[mi][1][r] +
                     acc[mi][2][r] * acc[mi][2][r] + acc[mi][3][r] * acc[mi][3][r];
        ssum += __shfl_xor(ssum, 1);
        ssum += __shfl_xor(ssum, 2);
        ssum += __shfl_xor(ssum, 4);
        ssum += __shfl_xor(ssum, 8);
        float rs = rsqrtf(ssum * (1.0f / 64.0f) + 1e-6f);
        int row = wm + mi * 16 + quad * 4 + r;       // row within block
        int s = (m0 & 2047) + row;                   // sequence position
        float nv[4];
#pragma unroll
        for (int ni = 0; ni < 4; ni++) nv[ni] = acc[mi][ni][r] * rs * wv4[ni];
#pragma unroll
        for (int ni = 0; ni < 4; ni++) {
          int d = ni * 16 + l15;
          float c = cosT[s * HD_ + d];
          float sn = sinT[s * HD_ + d];
          float partner = nv[ni ^ 2];                // d^32 lives in ni^2, same lane
          float rot = (ni < 2) ? -partner : partner; // rotate_half sign
          outp[(size_t)s * HD_ + d] = (__bf16)(nv[ni] * c + rot * sn);
        }
      }
    }
  } else {
    // V head: transpose-store (same scatter pattern norm_rope used)
    __bf16* vtp = VTo + ((size_t)b * NKV_ + (hh - 20)) * (size_t)HD_ * VP_;
#pragma unroll
    for (int mi = 0; mi < 4; mi++)
#pragma unroll
      for (int r = 0; r < 4; r++) {
        int row = wm + mi * 16 + quad * 4 + r;
        int s = (m0 & 2047) + row;
#pragma unroll
        for (int ni = 0; ni < 4; ni++) {
          int d = ni * 16 + l15;
          vtp[(size_t)d * VP_ + s] = (__bf16)acc[mi][ni][r];
        }
      }
  }
}

// ---------------- bf16 MFMA GEMM: 256x128 tile, BK=64, 8 waves, 2-phase dbuf -----------
// R10-exact (output projection; grid 256 = 1 block/CU; chunked XCD swizzle)
__global__ __launch_bounds__(512) void gemm_bf16_f32(const __bf16* __restrict__ A,
                                                     const __bf16* __restrict__ Bt,
                                                     float* __restrict__ C,
                                                     int M, int N, int K,
                                                     int lda, int ldb, int ldc) {
  __shared__ __align__(16) __bf16 As[2][256 * 64];
  __shared__ __align__(16) __bf16 Bs[2][128 * 64];
  int wid = threadIdx.x >> 6, lane = threadIdx.x & 63;
  int l15 = lane & 15, quad = lane >> 4;
  int wm = (wid >> 1) * 64, wn = (wid & 1) * 64; // 4m x 2n wave grid
  // chunked XCD swizzle (total % 8 == 0 required; 16x16=256 ok)
  int nbx = gridDim.x;
  int total = nbx * gridDim.y;
  int q = total >> 3;
  int lin = blockIdx.x + nbx * blockIdx.y;
  int virt = (lin & 7) * q + (lin >> 3);
  int m0 = (virt / nbx) * 256, n0 = (virt % nbx) * 128;
  int srow_off = lane >> 3;
  int gphys = lane & 7;
  floatx4 acc[4][4] = {};

  auto stage = [&](int bufi, int kb) {
#pragma unroll
    for (int j = 0; j < 4; j++) {
      int rbase = j * 64 + wid * 8;
      int row = rbase + srow_off;
      int glog = gphys ^ (row & 7);
      const __bf16* ga = &A[(size_t)(m0 + row) * lda + kb + glog * 8];
      __builtin_amdgcn_global_load_lds(GLB(ga), LDS(&As[bufi][rbase * 64]), 16, 0, 0);
    }
#pragma unroll
    for (int j = 0; j < 2; j++) {
      int rbase = j * 64 + wid * 8;
      int row = rbase + srow_off;
      int glog = gphys ^ (row & 7);
      const __bf16* gb = &Bt[(size_t)(n0 + row) * ldb + kb + glog * 8];
      __builtin_amdgcn_global_load_lds(GLB(gb), LDS(&Bs[bufi][rbase * 64]), 16, 0, 0);
    }
  };

  stage(0, 0);
  __syncthreads();
  int buf = 0;
  for (int kb = 0; kb < K; kb += 64) {
    if (kb + 64 < K) stage(buf ^ 1, kb + 64);
#pragma unroll
    for (int kk = 0; kk < 64; kk += 32) {
      int cgq = (kk >> 3) + quad;
      bfx8 af[4], bfr[4];
#pragma unroll
      for (int mi = 0; mi < 4; mi++) {
        int row = wm + mi * 16 + l15;
        af[mi] = *(const bfx8*)&As[buf][row * 64 + (cgq ^ (row & 7)) * 8];
      }
#pragma unroll
      for (int ni = 0; ni < 4; ni++) {
        int row = wn + ni * 16 + l15;
        bfr[ni] = *(const bfx8*)&Bs[buf][row * 64 + (cgq ^ (row & 7)) * 8];
      }
#pragma unroll
      for (int mi = 0; mi < 4; mi++)
#pragma unroll
        for (int ni = 0; ni < 4; ni++)
          acc[mi][ni] = __builtin_amdgcn_mfma_f32_16x16x32_bf16(af[mi], bfr[ni], acc[mi][ni], 0, 0, 0);
    }
    __syncthreads();
    buf ^= 1;
  }
#pragma unroll
  for (int mi = 0; mi < 4; mi++)
#pragma unroll
    for (int ni = 0; ni < 4; ni++) {
      int row = m0 + wm + mi * 16 + quad * 4;
      int coln = n0 + wn + ni * 16 + l15;
#pragma unroll
      for (int r = 0; r < 4; r++)
        C[(size_t)(row + r) * ldc + coln] = acc[mi][ni][r];
    }
}

// ---------------- flash attention (causal, GQA) + hosted wo-transpose blocks -----------
// Attention part is R4/R10-exact (best measured: 45.0us) — 4 waves, QBLK=64, reg-staged
// dbuf. Blocks with blockIdx.x >= 32 instead run one 32x32 wo-transpose tile (needed
// only by gemm2, which launches after this kernel): they co-reside in attn's spare
// LDS/thread slots and fill the tail holes left by attn's variable-duration blocks.
__global__ __launch_bounds__(256, 4) void attn_kernel(const __bf16* __restrict__ Q,
                                                      const __bf16* __restrict__ Kc,
                                                      const __bf16* __restrict__ VT,
                                                      __bf16* __restrict__ Ob,
                                                      const float* __restrict__ wo,
                                                      __bf16* __restrict__ woT) {
  __shared__ __align__(16) __bf16 Ks[64][72]; // [kv][hd]
  __shared__ __align__(16) __bf16 Vs[64][72]; // [hd][kv]
  __shared__ __align__(16) __bf16 Pst[4][16][72];

  if (blockIdx.x >= 32) {
    // ---- hosted wo transpose: woT[n][k] = wo[k][n], wo is 1024 x 2048 ----
    // tile id: n-tile = blockIdx.x - 32 (0..63), k-tile = h + 16*b (0..31)
    float (*tile)[33] = reinterpret_cast<float(*)[33]>(&Ks[0][0]); // 4224B < 9216B
    int n0 = (blockIdx.x - 32) * 32;
    int k0 = (blockIdx.y + NH_ * blockIdx.z) * 32;
    int tx = threadIdx.x & 31, ty = threadIdx.x >> 5;
#pragma unroll
    for (int r = 0; r < 32; r += 8)
      tile[ty + r][tx] = wo[(size_t)(k0 + ty + r) * H_ + n0 + tx];
    __syncthreads();
#pragma unroll
    for (int r = 0; r < 32; r += 8)
      woT[(size_t)(n0 + ty + r) * AP_ + k0 + tx] = (__bf16)tile[tx][ty + r];
    return;
  }

  int px = blockIdx.x, h = blockIdx.y, b = blockIdx.z;
  int u = (px + 2 * (h & 7)) & 31;
  int qt = (((h >> 3) ^ b) & 1) ? (31 - u) : u;
  int wid = threadIdx.x >> 6, lane = threadIdx.x & 63;
  int l15 = lane & 15, quad = lane >> 4;
  int q0 = qt * 64 + wid * 16;
  int kvh = h >> 2; // N_REP = 4
  const __bf16* Qh = Q + (((size_t)b * NH_ + h) * S_ + q0) * HD_;
  const __bf16* Kh = Kc + ((size_t)b * NKV_ + kvh) * S_ * HD_;
  const __bf16* Vh = VT + ((size_t)b * NKV_ + kvh) * (size_t)HD_ * VP_;
  __bf16 (*P)[72] = Pst[wid];

  int srow = threadIdx.x >> 3;         // 0..31
  int scol = (threadIdx.x & 7) * 8;    // element offset 0..56

  bfx8 qf0, qf1;
  {
    const __bf16* qp = Qh + l15 * HD_ + quad * 8;
    qf0 = *(const bfx8*)qp;
    qf1 = *(const bfx8*)(qp + 32);
  }
  floatx4 oacc[4] = {};
  float ps = 0.f;
  int ntiles = qt + 1; // causal, block-uniform
  bfx8 kpre0, kpre1, vpre0, vpre1;
  kpre0 = *(const bfx8*)&Kh[(size_t)srow * HD_ + scol];
  kpre1 = *(const bfx8*)&Kh[(size_t)(srow + 32) * HD_ + scol];
  vpre0 = *(const bfx8*)&Vh[(size_t)srow * VP_ + scol];
  vpre1 = *(const bfx8*)&Vh[(size_t)(srow + 32) * VP_ + scol];
  for (int kt = 0; kt < ntiles; kt++) {
    int kv0 = kt * 64;
    int dq = q0 - kv0;
    __syncthreads();
    *(bfx8*)&Ks[srow][scol] = kpre0;
    *(bfx8*)&Ks[srow + 32][scol] = kpre1;
    *(bfx8*)&Vs[srow][scol] = vpre0;
    *(bfx8*)&Vs[srow + 32][scol] = vpre1;
    __syncthreads();
    if (kt + 1 < ntiles) {
      int kn = kv0 + 64;
      kpre0 = *(const bfx8*)&Kh[(size_t)(kn + srow) * HD_ + scol];
      kpre1 = *(const bfx8*)&Kh[(size_t)(kn + srow + 32) * HD_ + scol];
      vpre0 = *(const bfx8*)&Vh[(size_t)srow * VP_ + kn + scol];
      vpre1 = *(const bfx8*)&Vh[(size_t)(srow + 32) * VP_ + kn + scol];
    }
    floatx4 sf[4];
#pragma unroll
    for (int nt = 0; nt < 4; nt++) {
      bfx8 kf0 = *(const bfx8*)&Ks[nt * 16 + l15][quad * 8];
      bfx8 kf1 = *(const bfx8*)&Ks[nt * 16 + l15][32 + quad * 8];
      floatx4 z = {0.f, 0.f, 0.f, 0.f};
      z = __builtin_amdgcn_mfma_f32_16x16x32_bf16(kf0, qf0, z, 0, 0, 0);
      sf[nt] = __builtin_amdgcn_mfma_f32_16x16x32_bf16(kf1, qf1, z, 0, 0, 0);
    }
#pragma unroll
    for (int nt = 0; nt < 4; nt++) {
      bfx4 pk;
#pragma unroll
      for (int r = 0; r < 4; r++) {
        int kvrel = nt * 16 + quad * 4 + r;
        float p = __expf(sf[nt][r] * 0.125f);
        p = (kvrel - l15 > dq) ? 0.f : p;
        ps += p;
        pk[r] = (__bf16)p;
      }
      *(bfx4*)&P[l15][nt * 16 + quad * 4] = pk;
    }
    bfx8 pa0 = *(const bfx8*)&P[l15][quad * 8];
    bfx8 pa1 = *(const bfx8*)&P[l15][32 + quad * 8];
#pragma unroll
    for (int ot = 0; ot < 4; ot++) {
      bfx8 vf0 = *(const bfx8*)&Vs[ot * 16 + l15][quad * 8];
      bfx8 vf1 = *(const bfx8*)&Vs[ot * 16 + l15][32 + quad * 8];
      oacc[ot] = __builtin_amdgcn_mfma_f32_16x16x32_bf16(pa0, vf0, oacc[ot], 0, 0, 0);
      oacc[ot] = __builtin_amdgcn_mfma_f32_16x16x32_bf16(pa1, vf1, oacc[ot], 0, 0, 0);
    }
  }
  ps += __shfl_xor(ps, 16);
  ps += __shfl_xor(ps, 32);
  float rl[4];
#pragma unroll
  for (int r = 0; r < 4; r++) rl[r] = 1.0f / __shfl(ps, quad * 4 + r);
#pragma unroll
  for (int ot = 0; ot < 4; ot++)
#pragma unroll
    for (int r = 0; r < 4; r++) {
      float val = oacc[ot][r] * rl[r];
      Ob[((size_t)b * S_ + q0 + quad * 4 + r) * AP_ + h * HD_ + ot * 16 + l15] = (__bf16)val;
    }
}

extern "C" void kernel_launch(void* const* d_in, const int* in_sizes, int n_in,
                              void* d_out, int out_size, void* d_ws, size_t ws_size,
                              hipStream_t stream) {
  const float* x   = (const float*)d_in[0];
  const float* cosT = (const float*)d_in[1];
  const float* sinT = (const float*)d_in[2];
  const float* wq  = (const float*)d_in[3];
  const float* wk  = (const float*)d_in[4];
  const float* wv  = (const float*)d_in[5];
  const float* wo  = (const float*)d_in[6];
  const float* qw  = (const float*)d_in[7];
  const float* kw  = (const float*)d_in[8];
  float* out = (float*)d_out;

  char* w = (char*)d_ws;
  // Straight-line workspace (fused gemm reads xbf while writing Q/K/VT; no aliasing):
  __bf16* xbf   = (__bf16*)(w);                        // 4096*2112*2 = 17,301,504
  __bf16* wqkvT = (__bf16*)(w + 17301504);             // 1536*2112*2 =  6,488,064
  __bf16* woT   = (__bf16*)(w + 23789568);             // 2048*1088*2 =  4,456,448
  __bf16* Qb    = (__bf16*)(w + 28246016);             //  8,388,608
  __bf16* Kb    = (__bf16*)(w + 36634624);             //  2,097,152
  __bf16* VTb   = (__bf16*)(w + 38731776);             // 2*4*64*2112*2 = 2,162,688
  __bf16* attnO = (__bf16*)(w + 40894464);             // 4096*1088*2 = 8,912,896 (end 49,807,360)

  // prep: cast (4096 blocks) + wq/wk/wv transposes (2048+512+512) — wo moved to attn
  prep_kernel<<<M_ + 3072, 256, 0, stream>>>(x, wq, wk, wv, xbf, wqkvT);
  // QKV GEMM + RMSNorm/RoPE/layout epilogue: 128x128 dbuf + XCD swizzle,
  // grid 12 x 32 = 384 blocks (R10-exact)
  gemm_qkv_fused<<<dim3(12, 32), 256, 0, stream>>>(
      xbf, wqkvT, cosT, sinT, qw, kw, Qb, Kb, VTb);
  // attention (x<32) + hosted wo-transpose (x in [32,96)): grid 96 x 16 x 2
  attn_kernel<<<dim3(96, NH_, B_), 256, 0, stream>>>(Qb, Kb, VTb, attnO, wo, woT);
  // output GEMM, 256x128 dbuf + XCD swizzle: grid 16 x 16 = 256 blocks (R10-exact)
  gemm_bf16_f32<<<dim3(H_ / 128, M_ / 256), 512, 0, stream>>>(
      attnO, woT, out, M_, H_, HQ_, AP_, AP_, H_);
}

// Round 14
// 212.534 us; speedup vs baseline: 1.0846x; 1.0846x over previous
//
#include <hip/hip_runtime.h>

typedef float floatx4 __attribute__((ext_vector_type(4)));
typedef __bf16 bfx8 __attribute__((ext_vector_type(8)));
typedef __bf16 bfx4 __attribute__((ext_vector_type(4)));

// Problem constants
constexpr int B_ = 2, S_ = 2048, H_ = 2048, NH_ = 16, NKV_ = 4, HD_ = 64;
constexpr int M_ = B_ * S_;               // 4096 rows
constexpr int NQKV_ = NH_ * HD_ + 2 * NKV_ * HD_; // 1536
constexpr int HQ_ = NH_ * HD_;            // 1024
// Pitches: 128B-aligned (no cache-line straddle on 128B DMA row-chunks) AND an
// odd multiple of 64 elements (33x128B / 17x128B) to keep channel spread.
constexpr int XP_ = 2112;  // xbf / wqkvT pitch (4224B = 33*128)
constexpr int AP_ = 1088;  // attn-out / woT pitch (2176B = 17*128)
constexpr int VP_ = 2112;  // V-transposed pitch

#define GLB(p) ((const __attribute__((address_space(1))) void*)(p))
#define LDS(p) ((__attribute__((address_space(3))) void*)(p))

// ---------------- fused prep: fp32->bf16 cast of x  +  all 4 weight transposes ----------
__global__ __launch_bounds__(256) void prep_kernel(const float* __restrict__ x,
                                                   const float* __restrict__ wq,
                                                   const float* __restrict__ wk,
                                                   const float* __restrict__ wv,
                                                   const float* __restrict__ wo,
                                                   __bf16* __restrict__ xbf,
                                                   __bf16* __restrict__ wqkvT,
                                                   __bf16* __restrict__ woT) {
  __shared__ float tile[32][33];
  int bid = blockIdx.x;
  if (bid < M_) {
    // ---- cast branch ----
    const float4* s = (const float4*)(x + (size_t)bid * H_);
    __bf16* d = xbf + (size_t)bid * XP_;
#pragma unroll
    for (int i = 0; i < 2; i++) {
      int c = i * 256 + threadIdx.x;
      float4 v = s[c];
      bfx4 o;
      o[0] = (__bf16)v.x; o[1] = (__bf16)v.y; o[2] = (__bf16)v.z; o[3] = (__bf16)v.w;
      *(bfx4*)(d + c * 4) = o;
    }
    return;
  }
  bid -= M_;
  const float* src; __bf16* dst; int N, dstOff, pitch, nbx;
  if (bid < 2048)      { src = wq; dst = wqkvT; N = 1024; dstOff = 0;    pitch = XP_; nbx = 32; }
  else if (bid < 2560) { bid -= 2048; src = wk; dst = wqkvT; N = 256; dstOff = 1024; pitch = XP_; nbx = 8; }
  else if (bid < 3072) { bid -= 2560; src = wv; dst = wqkvT; N = 256; dstOff = 1280; pitch = XP_; nbx = 8; }
  else                 { bid -= 3072; src = wo; dst = woT;   N = 2048; dstOff = 0;   pitch = AP_; nbx = 64; }
  int n0 = (bid % nbx) * 32, k0 = (bid / nbx) * 32;
  int tx = threadIdx.x & 31, ty = threadIdx.x >> 5; // (32,8) layout
#pragma unroll
  for (int r = 0; r < 32; r += 8)
    tile[ty + r][tx] = src[(size_t)(k0 + ty + r) * N + n0 + tx];
  __syncthreads();
#pragma unroll
  for (int r = 0; r < 32; r += 8)
    dst[(size_t)(n0 + ty + r + dstOff) * pitch + k0 + tx] = (__bf16)tile[tx][ty + r];
}

// ---------------- fused QKV GEMM + RMSNorm + RoPE + attention-layout epilogue -----------
// R10-exact (best measured, 46.2us / wall 212.8): 128x128 tile, BK=64, 4 waves (2x2),
// 2-phase LDS double-buffer with __syncthreads, 384 blocks + chunked XCD swizzle
// (FETCH 75.9->33.9MB). R11 proved counted-vmcnt adds nothing here: the stall is
// DMA-issue/L2-service throughput, not the barrier drain.
__global__ __launch_bounds__(256) void gemm_qkv_fused(const __bf16* __restrict__ A,
                                                      const __bf16* __restrict__ Bt,
                                                      const float* __restrict__ cosT,
                                                      const float* __restrict__ sinT,
                                                      const float* __restrict__ qw,
                                                      const float* __restrict__ kw,
                                                      __bf16* __restrict__ Qo,
                                                      __bf16* __restrict__ Ko,
                                                      __bf16* __restrict__ VTo) {
  __shared__ __align__(16) __bf16 As[2][128 * 64];
  __shared__ __align__(16) __bf16 Bs[2][128 * 64];
  int wid = threadIdx.x >> 6, lane = threadIdx.x & 63;
  int l15 = lane & 15, quad = lane >> 4;
  int wm = (wid >> 1) * 64, wn = (wid & 1) * 64;
  // chunked XCD swizzle (384 = 8 x 48, bijective)
  int lin = blockIdx.x + 12 * blockIdx.y;
  int virt = (lin & 7) * 48 + (lin >> 3);
  int m0 = (virt / 12) * 128, n0 = (virt % 12) * 128;
  int srow_off = lane >> 3;
  int gphys = lane & 7;
  floatx4 acc[4][4] = {};

  // ---- staging helper (issue only; no wait) ----
  auto stage = [&](int bufi, int kb) {
#pragma unroll
    for (int j = 0; j < 4; j++) {
      int rbase = wid * 32 + j * 8;
      int row = rbase + srow_off;
      int glog = gphys ^ (row & 7);
      const __bf16* ga = &A[(size_t)(m0 + row) * XP_ + kb + glog * 8];
      const __bf16* gb = &Bt[(size_t)(n0 + row) * XP_ + kb + glog * 8];
      __builtin_amdgcn_global_load_lds(GLB(ga), LDS(&As[bufi][rbase * 64]), 16, 0, 0);
      __builtin_amdgcn_global_load_lds(GLB(gb), LDS(&Bs[bufi][rbase * 64]), 16, 0, 0);
    }
  };

  stage(0, 0);
  __syncthreads(); // buf0 ready
  int buf = 0;
  for (int kb = 0; kb < H_; kb += 64) {
    if (kb + 64 < H_) stage(buf ^ 1, kb + 64); // prefetch next tile (overlaps compute)
#pragma unroll
    for (int kk = 0; kk < 64; kk += 32) {
      int cgq = (kk >> 3) + quad;
      bfx8 af[4], bfr[4];
#pragma unroll
      for (int mi = 0; mi < 4; mi++) {
        int row = wm + mi * 16 + l15;
        af[mi] = *(const bfx8*)&As[buf][row * 64 + (cgq ^ (row & 7)) * 8];
      }
#pragma unroll
      for (int ni = 0; ni < 4; ni++) {
        int row = wn + ni * 16 + l15;
        bfr[ni] = *(const bfx8*)&Bs[buf][row * 64 + (cgq ^ (row & 7)) * 8];
      }
#pragma unroll
      for (int mi = 0; mi < 4; mi++)
#pragma unroll
        for (int ni = 0; ni < 4; ni++)
          acc[mi][ni] = __builtin_amdgcn_mfma_f32_16x16x32_bf16(af[mi], bfr[ni], acc[mi][ni], 0, 0, 0);
    }
    __syncthreads(); // drains remaining prefetch + protects buf overwrite next iter
    buf ^= 1;
  }
  // ---------------- fused epilogue ----------------
  // acc[mi][ni][r] = C[m0+wm+mi*16+quad*4+r][n0+wn+ni*16+l15]
  int hh = (n0 + wn) >> 6;   // wave-uniform head id: 0..15 q, 16..19 k, 20..23 v
  int b = m0 >> 11;          // whole block within one batch (m0 mult of 128)
  if (hh < 20) {
    const float* wptr = (hh < 16) ? qw : kw;
    float wv4[4];
#pragma unroll
    for (int ni = 0; ni < 4; ni++) wv4[ni] = wptr[ni * 16 + l15];
    __bf16* outp = (hh < 16) ? (Qo + (((size_t)b * NH_ + hh) * S_) * HD_)
                             : (Ko + (((size_t)b * NKV_ + (hh - 16)) * S_) * HD_);
#pragma unroll
    for (int mi = 0; mi < 4; mi++) {
#pragma unroll
      for (int r = 0; r < 4; r++) {
        // RMSNorm: sum of squares over the head's 64 cols (4 regs x 16 lanes)
        float ssum = acc[mi][0][r] * acc[mi][0][r] + acc[mi][1][r] * acc[mi][1][r] +
                     acc[mi][2][r] * acc[mi][2][r] + acc[mi][3][r] * acc[mi][3][r];
        ssum += __shfl_xor(ssum, 1);
        ssum += __shfl_xor(ssum, 2);
        ssum += __shfl_xor(ssum, 4);
        ssum += __shfl_xor(ssum, 8);
        float rs = rsqrtf(ssum * (1.0f / 64.0f) + 1e-6f);
        int row = wm + mi * 16 + quad * 4 + r;       // row within block
        int s = (m0 & 2047) + row;                   // sequence position
        float nv[4];
#pragma unroll
        for (int ni = 0; ni < 4; ni++) nv[ni] = acc[mi][ni][r] * rs * wv4[ni];
#pragma unroll
        for (int ni = 0; ni < 4; ni++) {
          int d = ni * 16 + l15;
          float c = cosT[s * HD_ + d];
          float sn = sinT[s * HD_ + d];
          float partner = nv[ni ^ 2];                // d^32 lives in ni^2, same lane
          float rot = (ni < 2) ? -partner : partner; // rotate_half sign
          outp[(size_t)s * HD_ + d] = (__bf16)(nv[ni] * c + rot * sn);
        }
      }
    }
  } else {
    // V head: transpose-store (same scatter pattern norm_rope used)
    __bf16* vtp = VTo + ((size_t)b * NKV_ + (hh - 20)) * (size_t)HD_ * VP_;
#pragma unroll
    for (int mi = 0; mi < 4; mi++)
#pragma unroll
      for (int r = 0; r < 4; r++) {
        int row = wm + mi * 16 + quad * 4 + r;
        int s = (m0 & 2047) + row;
#pragma unroll
        for (int ni = 0; ni < 4; ni++) {
          int d = ni * 16 + l15;
          vtp[(size_t)d * VP_ + s] = (__bf16)acc[mi][ni][r];
        }
      }
  }
}

// ---------------- bf16 MFMA GEMM: 256x128 tile, BK=64, 8 waves, 2-phase dbuf -----------
// R10-exact (output projection; grid 256 = 1 block/CU; chunked XCD swizzle)
__global__ __launch_bounds__(512) void gemm_bf16_f32(const __bf16* __restrict__ A,
                                                     const __bf16* __restrict__ Bt,
                                                     float* __restrict__ C,
                                                     int M, int N, int K,
                                                     int lda, int ldb, int ldc) {
  __shared__ __align__(16) __bf16 As[2][256 * 64];
  __shared__ __align__(16) __bf16 Bs[2][128 * 64];
  int wid = threadIdx.x >> 6, lane = threadIdx.x & 63;
  int l15 = lane & 15, quad = lane >> 4;
  int wm = (wid >> 1) * 64, wn = (wid & 1) * 64; // 4m x 2n wave grid
  // chunked XCD swizzle (total % 8 == 0 required; 16x16=256 ok)
  int nbx = gridDim.x;
  int total = nbx * gridDim.y;
  int q = total >> 3;
  int lin = blockIdx.x + nbx * blockIdx.y;
  int virt = (lin & 7) * q + (lin >> 3);
  int m0 = (virt / nbx) * 256, n0 = (virt % nbx) * 128;
  int srow_off = lane >> 3;
  int gphys = lane & 7;
  floatx4 acc[4][4] = {};

  auto stage = [&](int bufi, int kb) {
#pragma unroll
    for (int j = 0; j < 4; j++) {
      int rbase = j * 64 + wid * 8;
      int row = rbase + srow_off;
      int glog = gphys ^ (row & 7);
      const __bf16* ga = &A[(size_t)(m0 + row) * lda + kb + glog * 8];
      __builtin_amdgcn_global_load_lds(GLB(ga), LDS(&As[bufi][rbase * 64]), 16, 0, 0);
    }
#pragma unroll
    for (int j = 0; j < 2; j++) {
      int rbase = j * 64 + wid * 8;
      int row = rbase + srow_off;
      int glog = gphys ^ (row & 7);
      const __bf16* gb = &Bt[(size_t)(n0 + row) * ldb + kb + glog * 8];
      __builtin_amdgcn_global_load_lds(GLB(gb), LDS(&Bs[bufi][rbase * 64]), 16, 0, 0);
    }
  };

  stage(0, 0);
  __syncthreads();
  int buf = 0;
  for (int kb = 0; kb < K; kb += 64) {
    if (kb + 64 < K) stage(buf ^ 1, kb + 64);
#pragma unroll
    for (int kk = 0; kk < 64; kk += 32) {
      int cgq = (kk >> 3) + quad;
      bfx8 af[4], bfr[4];
#pragma unroll
      for (int mi = 0; mi < 4; mi++) {
        int row = wm + mi * 16 + l15;
        af[mi] = *(const bfx8*)&As[buf][row * 64 + (cgq ^ (row & 7)) * 8];
      }
#pragma unroll
      for (int ni = 0; ni < 4; ni++) {
        int row = wn + ni * 16 + l15;
        bfr[ni] = *(const bfx8*)&Bs[buf][row * 64 + (cgq ^ (row & 7)) * 8];
      }
#pragma unroll
      for (int mi = 0; mi < 4; mi++)
#pragma unroll
        for (int ni = 0; ni < 4; ni++)
          acc[mi][ni] = __builtin_amdgcn_mfma_f32_16x16x32_bf16(af[mi], bfr[ni], acc[mi][ni], 0, 0, 0);
    }
    __syncthreads();
    buf ^= 1;
  }
#pragma unroll
  for (int mi = 0; mi < 4; mi++)
#pragma unroll
    for (int ni = 0; ni < 4; ni++) {
      int row = m0 + wm + mi * 16 + quad * 4;
      int coln = n0 + wn + ni * 16 + l15;
#pragma unroll
      for (int r = 0; r < 4; r++)
        C[(size_t)(row + r) * ldc + coln] = acc[mi][ni][r];
    }
}

// ---------------- flash attention (causal, GQA), block-cooperative LDS staging ----------
// R4/R10-exact (best measured: 45.0us) — 4 waves, QBLK=64, reg-staged double-buffer.
__global__ __launch_bounds__(256, 4) void attn_kernel(const __bf16* __restrict__ Q,
                                                      const __bf16* __restrict__ Kc,
                                                      const __bf16* __restrict__ VT,
                                                      __bf16* __restrict__ Ob) {
  int px = blockIdx.x, h = blockIdx.y, b = blockIdx.z;
  int u = (px + 2 * (h & 7)) & 31;
  int qt = (((h >> 3) ^ b) & 1) ? (31 - u) : u;
  int wid = threadIdx.x >> 6, lane = threadIdx.x & 63;
  int l15 = lane & 15, quad = lane >> 4;
  int q0 = qt * 64 + wid * 16;
  int kvh = h >> 2; // N_REP = 4
  const __bf16* Qh = Q + (((size_t)b * NH_ + h) * S_ + q0) * HD_;
  const __bf16* Kh = Kc + ((size_t)b * NKV_ + kvh) * S_ * HD_;
  const __bf16* Vh = VT + ((size_t)b * NKV_ + kvh) * (size_t)HD_ * VP_;
  __shared__ __align__(16) __bf16 Ks[64][72]; // [kv][hd]
  __shared__ __align__(16) __bf16 Vs[64][72]; // [hd][kv]
  __shared__ __align__(16) __bf16 Pst[4][16][72];
  __bf16 (*P)[72] = Pst[wid];

  int srow = threadIdx.x >> 3;         // 0..31
  int scol = (threadIdx.x & 7) * 8;    // element offset 0..56

  bfx8 qf0, qf1;
  {
    const __bf16* qp = Qh + l15 * HD_ + quad * 8;
    qf0 = *(const bfx8*)qp;
    qf1 = *(const bfx8*)(qp + 32);
  }
  floatx4 oacc[4] = {};
  float ps = 0.f;
  int ntiles = qt + 1; // causal, block-uniform
  bfx8 kpre0, kpre1, vpre0, vpre1;
  kpre0 = *(const bfx8*)&Kh[(size_t)srow * HD_ + scol];
  kpre1 = *(const bfx8*)&Kh[(size_t)(srow + 32) * HD_ + scol];
  vpre0 = *(const bfx8*)&Vh[(size_t)srow * VP_ + scol];
  vpre1 = *(const bfx8*)&Vh[(size_t)(srow + 32) * VP_ + scol];
  for (int kt = 0; kt < ntiles; kt++) {
    int kv0 = kt * 64;
    int dq = q0 - kv0;
    __syncthreads();
    *(bfx8*)&Ks[srow][scol] = kpre0;
    *(bfx8*)&Ks[srow + 32][scol] = kpre1;
    *(bfx8*)&Vs[srow][scol] = vpre0;
    *(bfx8*)&Vs[srow + 32][scol] = vpre1;
    __syncthreads();
    if (kt + 1 < ntiles) {
      int kn = kv0 + 64;
      kpre0 = *(const bfx8*)&Kh[(size_t)(kn + srow) * HD_ + scol];
      kpre1 = *(const bfx8*)&Kh[(size_t)(kn + srow + 32) * HD_ + scol];
      vpre0 = *(const bfx8*)&Vh[(size_t)srow * VP_ + kn + scol];
      vpre1 = *(const bfx8*)&Vh[(size_t)(srow + 32) * VP_ + kn + scol];
    }
    floatx4 sf[4];
#pragma unroll
    for (int nt = 0; nt < 4; nt++) {
      bfx8 kf0 = *(const bfx8*)&Ks[nt * 16 + l15][quad * 8];
      bfx8 kf1 = *(const bfx8*)&Ks[nt * 16 + l15][32 + quad * 8];
      floatx4 z = {0.f, 0.f, 0.f, 0.f};
      z = __builtin_amdgcn_mfma_f32_16x16x32_bf16(kf0, qf0, z, 0, 0, 0);
      sf[nt] = __builtin_amdgcn_mfma_f32_16x16x32_bf16(kf1, qf1, z, 0, 0, 0);
    }
#pragma unroll
    for (int nt = 0; nt < 4; nt++) {
      bfx4 pk;
#pragma unroll
      for (int r = 0; r < 4; r++) {
        int kvrel = nt * 16 + quad * 4 + r;
        float p = __expf(sf[nt][r] * 0.125f);
        p = (kvrel - l15 > dq) ? 0.f : p;
        ps += p;
        pk[r] = (__bf16)p;
      }
      *(bfx4*)&P[l15][nt * 16 + quad * 4] = pk;
    }
    bfx8 pa0 = *(const bfx8*)&P[l15][quad * 8];
    bfx8 pa1 = *(const bfx8*)&P[l15][32 + quad * 8];
#pragma unroll
    for (int ot = 0; ot < 4; ot++) {
      bfx8 vf0 = *(const bfx8*)&Vs[ot * 16 + l15][quad * 8];
      bfx8 vf1 = *(const bfx8*)&Vs[ot * 16 + l15][32 + quad * 8];
      oacc[ot] = __builtin_amdgcn_mfma_f32_16x16x32_bf16(pa0, vf0, oacc[ot], 0, 0, 0);
      oacc[ot] = __builtin_amdgcn_mfma_f32_16x16x32_bf16(pa1, vf1, oacc[ot], 0, 0, 0);
    }
  }
  ps += __shfl_xor(ps, 16);
  ps += __shfl_xor(ps, 32);
  float rl[4];
#pragma unroll
  for (int r = 0; r < 4; r++) rl[r] = 1.0f / __shfl(ps, quad * 4 + r);
#pragma unroll
  for (int ot = 0; ot < 4; ot++)
#pragma unroll
    for (int r = 0; r < 4; r++) {
      float val = oacc[ot][r] * rl[r];
      Ob[((size_t)b * S_ + q0 + quad * 4 + r) * AP_ + h * HD_ + ot * 16 + l15] = (__bf16)val;
    }
}

extern "C" void kernel_launch(void* const* d_in, const int* in_sizes, int n_in,
                              void* d_out, int out_size, void* d_ws, size_t ws_size,
                              hipStream_t stream) {
  const float* x   = (const float*)d_in[0];
  const float* cosT = (const float*)d_in[1];
  const float* sinT = (const float*)d_in[2];
  const float* wq  = (const float*)d_in[3];
  const float* wk  = (const float*)d_in[4];
  const float* wv  = (const float*)d_in[5];
  const float* wo  = (const float*)d_in[6];
  const float* qw  = (const float*)d_in[7];
  const float* kw  = (const float*)d_in[8];
  float* out = (float*)d_out;

  char* w = (char*)d_ws;
  // Straight-line workspace (fused gemm reads xbf while writing Q/K/VT; no aliasing):
  __bf16* xbf   = (__bf16*)(w);                        // 4096*2112*2 = 17,301,504
  __bf16* wqkvT = (__bf16*)(w + 17301504);             // 1536*2112*2 =  6,488,064
  __bf16* woT   = (__bf16*)(w + 23789568);             // 2048*1088*2 =  4,456,448
  __bf16* Qb    = (__bf16*)(w + 28246016);             //  8,388,608
  __bf16* Kb    = (__bf16*)(w + 36634624);             //  2,097,152
  __bf16* VTb   = (__bf16*)(w + 38731776);             // 2*4*64*2112*2 = 2,162,688
  __bf16* attnO = (__bf16*)(w + 40894464);             // 4096*1088*2 = 8,912,896 (end 49,807,360)

  // fused prep: cast (4096 blocks) + wq/wk/wv/wo transposes (2048+512+512+2048)
  prep_kernel<<<M_ + 5120, 256, 0, stream>>>(x, wq, wk, wv, wo, xbf, wqkvT, woT);
  // QKV GEMM + RMSNorm/RoPE/layout epilogue: 128x128 dbuf + XCD swizzle,
  // grid 12 x 32 = 384 blocks (R10-exact)
  gemm_qkv_fused<<<dim3(12, 32), 256, 0, stream>>>(
      xbf, wqkvT, cosT, sinT, qw, kw, Qb, Kb, VTb);
  // attention: QBLK=64, 4 waves, grid 32 x 16 x 2 = 1024 blocks (R4/R10-exact)
  attn_kernel<<<dim3(32, NH_, B_), 256, 0, stream>>>(Qb, Kb, VTb, attnO);
  // output GEMM, 256x128 dbuf + XCD swizzle: grid 16 x 16 = 256 blocks (R10-exact)
  gemm_bf16_f32<<<dim3(H_ / 128, M_ / 256), 512, 0, stream>>>(
      attnO, woT, out, M_, H_, HQ_, AP_, AP_, H_);
}